// Round 3
// baseline (330.464 us; speedup 1.0000x reference)
//
#include <hip/hip_runtime.h>
#include <hip/hip_bf16.h>
#include <hip/hip_fp16.h>
#include <type_traits>

constexpr int BB = 4;
constexpr int CC = 512;
constexpr int HH = 4096;
constexpr int IC = 256;

typedef _Float16 f16x8v __attribute__((ext_vector_type(8)));
typedef __bf16   bf16x8v __attribute__((ext_vector_type(8)));
typedef float    f32x4v __attribute__((ext_vector_type(4)));

// ---------------------------------------------------------------------------
// async global -> LDS, 16 bytes per lane
// ---------------------------------------------------------------------------
__device__ __forceinline__ void gll16(const void* g, void* l) {
  __builtin_amdgcn_global_load_lds(
      (const __attribute__((address_space(1))) unsigned int*)g,
      (__attribute__((address_space(3))) unsigned int*)l, 16, 0, 0);
}

__device__ __forceinline__ f32x4v mfma16(f16x8v a, f16x8v b, f32x4v c) {
  return __builtin_amdgcn_mfma_f32_16x16x32_f16(a, b, c, 0, 0, 0);
}
__device__ __forceinline__ f32x4v mfma16(bf16x8v a, bf16x8v b, f32x4v c) {
  return __builtin_amdgcn_mfma_f32_16x16x32_bf16(a, b, c, 0, 0, 0);
}

// ---------------------------------------------------------------------------
// 128x128-tile B^T GEMM: C[m,n] = sum_k A[m,k] * B[n,k]; A,B k-contiguous.
// 256 threads = 4 waves, each wave a 64x64 quadrant (4x4 MFMA tiles).
// MODE 0: DUAL theta+phi: blockIdx.z = b + 4*which; which selects
//         {Ball,bias,outP} vs {Ball2,bias2,out2P}. fp16 store v + bias[n].
// MODE 1: bf16 store  out[m*N+n] = v + bias[m]        (g proj, [IC,H])
// MODE 2: bf16 store  out[m*N+n] = exp(v); Z[b,n] += column sums (scores)
// MODE 3: fp32 store  out[m*N+n] = v + bias[m] + xres (final + residual)
// Element type: fp16 for MODE 0/1/2, bf16 for MODE 3.
// ---------------------------------------------------------------------------
template <int MODE>
__launch_bounds__(256)
__global__ void mgemm128(const void* __restrict__ Aall, const void* __restrict__ Ball,
                         const void* __restrict__ Ball2,
                         void* __restrict__ outP, void* __restrict__ out2P,
                         const float* __restrict__ bias, const float* __restrict__ bias2,
                         const float* __restrict__ xres, float* __restrict__ Z,
                         int M, int N, int K,
                         size_t sAb, size_t sBb, size_t sOb) {
  using ET = typename std::conditional<MODE == 3, bf16x8v, f16x8v>::type;

  __shared__ __align__(16) unsigned short sA[128 * 32];
  __shared__ __align__(16) unsigned short sB[128 * 32];

  const int zz = blockIdx.z;
  int b, which;
  if constexpr (MODE == 0) { b = zz & (BB - 1); which = zz >> 2; }
  else { b = zz; which = 0; }

  const unsigned short* __restrict__ A = (const unsigned short*)Aall + (size_t)b * sAb;
  const unsigned short* __restrict__ Bm =
      (const unsigned short*)(which ? Ball2 : Ball) + (size_t)b * sBb;
  const float* __restrict__ biasSel = which ? bias2 : bias;
  void* __restrict__ outSel = which ? out2P : outP;

  const int t = threadIdx.x;
  const int lane = t & 63;
  const int w = t >> 6;
  const int wm = (w >> 1) << 6;
  const int wn = (w & 1) << 6;
  const int mBase = blockIdx.y * 128;
  const int nBase = blockIdx.x * 128;

  const int fr = lane & 15;
  const int fo = (lane >> 4) << 3;

  f32x4v acc[4][4] = {};

  for (int k0 = 0; k0 < K; k0 += 32) {
#pragma unroll
    for (int p = 0; p < 2; ++p) {
      const int u = t + (p << 8);
      const int r = u >> 2;
      const int cs = (u & 3) << 3;
      gll16(A + (size_t)(mBase + r) * K + (k0 + cs), sA + u * 8);
      gll16(Bm + (size_t)(nBase + r) * K + (k0 + cs), sB + u * 8);
    }
    __syncthreads();
    ET af[4], bf[4];
#pragma unroll
    for (int i = 0; i < 4; ++i)
      af[i] = *(const ET*)(sA + ((wm + (i << 4) + fr) << 5) + fo);
#pragma unroll
    for (int j = 0; j < 4; ++j)
      bf[j] = *(const ET*)(sB + ((wn + (j << 4) + fr) << 5) + fo);
#pragma unroll
    for (int i = 0; i < 4; ++i)
#pragma unroll
      for (int j = 0; j < 4; ++j)
        acc[i][j] = mfma16(af[i], bf[j], acc[i][j]);
    __syncthreads();
  }

  // C/D layout (verified m89/m91): col = lane&15, row = (lane>>4)*4 + reg
  const int row0 = (lane >> 4) << 2;
  const int col = lane & 15;

  if constexpr (MODE == 2) {
    __hip_bfloat16* __restrict__ outB = (__hip_bfloat16*)outP;
    float csum[4] = {0.f, 0.f, 0.f, 0.f};
#pragma unroll
    for (int i = 0; i < 4; ++i) {
      const int m0 = mBase + wm + (i << 4) + row0;
#pragma unroll
      for (int j = 0; j < 4; ++j) {
        const int n = nBase + wn + (j << 4) + col;
        __hip_bfloat16* dst = outB + (size_t)b * sOb + (size_t)m0 * N + n;
#pragma unroll
        for (int rg = 0; rg < 4; ++rg) {
          const float e = __expf(acc[i][j][rg]);
          dst[(size_t)rg * N] = __float2bfloat16(e);
          csum[j] += e;
        }
      }
    }
#pragma unroll
    for (int j = 0; j < 4; ++j) {
      float s = csum[j];
      s += __shfl_xor(s, 16, 64);
      s += __shfl_xor(s, 32, 64);
      if (lane < 16) {
        const int n = nBase + wn + (j << 4) + col;
        atomicAdd(&Z[(size_t)b * N + n], s);
      }
    }
  } else {
#pragma unroll
    for (int i = 0; i < 4; ++i) {
      const int m0 = mBase + wm + (i << 4) + row0;
#pragma unroll
      for (int j = 0; j < 4; ++j) {
        const int n = nBase + wn + (j << 4) + col;
#pragma unroll
        for (int rg = 0; rg < 4; ++rg) {
          const int m = m0 + rg;
          const float v = acc[i][j][rg];
          if constexpr (MODE == 0) {
            ((__half*)outSel)[(size_t)b * sOb + (size_t)m * N + n] =
                __float2half(v + biasSel[n]);
          } else if constexpr (MODE == 1) {
            ((__hip_bfloat16*)outP)[(size_t)b * sOb + (size_t)m * N + n] =
                __float2bfloat16(v + bias[m]);
          } else {
            const size_t o = (size_t)b * sOb + (size_t)m * N + n;
            ((float*)outP)[o] = v + bias[m] + xres[o];
          }
        }
      }
    }
  }
}

// ---------------------------------------------------------------------------
// ag GEMM, split-K: tile 64(m) x 256(n), K-chunk = 1024.
// grid = (KS=4, H/64, B) = 1024 blocks -> 4 blocks/CU, 16 waves/CU.
// A = E [H,H] bf16, B = gs [IC,H] bf16 (both k-contiguous).
// Partial sums atomicAdd'ed into agF fp32 [H,IC] (pre-zeroed).
// ---------------------------------------------------------------------------
__launch_bounds__(256)
__global__ void mgemm_ag(const __hip_bfloat16* __restrict__ Eall,
                         const __hip_bfloat16* __restrict__ Gall,
                         float* __restrict__ agF) {
  constexpr int KC = 1024;
  __shared__ __align__(16) unsigned short sA[64 * 32];
  __shared__ __align__(16) unsigned short sB[256 * 32];

  const int b = blockIdx.z;
  const int k0base = blockIdx.x * KC;
  const unsigned short* __restrict__ A =
      (const unsigned short*)Eall + (size_t)b * HH * HH;
  const unsigned short* __restrict__ G =
      (const unsigned short*)Gall + (size_t)b * IC * HH;

  const int t = threadIdx.x;
  const int lane = t & 63;
  const int w = t >> 6;
  const int wn = w << 6;
  const int mBase = blockIdx.y * 64;

  const int fr = lane & 15;
  const int fo = (lane >> 4) << 3;

  f32x4v acc[4][4] = {};

#pragma unroll 2
  for (int kk = 0; kk < KC; kk += 32) {
    const int k0 = k0base + kk;
    {
      const int r = t >> 2;
      const int cs = (t & 3) << 3;
      gll16(A + (size_t)(mBase + r) * HH + (k0 + cs), sA + t * 8);
    }
#pragma unroll
    for (int p = 0; p < 4; ++p) {
      const int u = t + (p << 8);
      const int r = u >> 2;
      const int cs = (u & 3) << 3;
      gll16(G + (size_t)r * HH + (k0 + cs), sB + u * 8);
    }
    __syncthreads();
    bf16x8v af[4], bf[4];
#pragma unroll
    for (int i = 0; i < 4; ++i)
      af[i] = *(const bf16x8v*)(sA + (((i << 4) + fr) << 5) + fo);
#pragma unroll
    for (int j = 0; j < 4; ++j)
      bf[j] = *(const bf16x8v*)(sB + ((wn + (j << 4) + fr) << 5) + fo);
#pragma unroll
    for (int i = 0; i < 4; ++i)
#pragma unroll
      for (int j = 0; j < 4; ++j)
        acc[i][j] = mfma16(af[i], bf[j], acc[i][j]);
    __syncthreads();
  }

  const int row0 = (lane >> 4) << 2;
  const int col = lane & 15;
  float* __restrict__ agb = agF + (size_t)b * HH * IC;
#pragma unroll
  for (int i = 0; i < 4; ++i) {
#pragma unroll
    for (int j = 0; j < 4; ++j) {
      const int n = wn + (j << 4) + col;
#pragma unroll
      for (int rg = 0; rg < 4; ++rg) {
        const int m = mBase + (i << 4) + row0 + rg;
        atomicAdd(&agb[(size_t)m * IC + n], acc[i][j][rg]);
      }
    }
  }
}

// agF fp32 [B*H*IC] -> agB bf16 (4 elems/thread)
__launch_bounds__(256)
__global__ void cvt_ag(const float* __restrict__ agF, __hip_bfloat16* __restrict__ agB) {
  const size_t tIdx = (size_t)blockIdx.x * 256 + threadIdx.x;
  const float4 v = ((const float4*)agF)[tIdx];
  ushort4 o;
  __hip_bfloat16 h0 = __float2bfloat16(v.x), h1 = __float2bfloat16(v.y);
  __hip_bfloat16 h2 = __float2bfloat16(v.z), h3 = __float2bfloat16(v.w);
  __builtin_memcpy(&o.x, &h0, 2); __builtin_memcpy(&o.y, &h1, 2);
  __builtin_memcpy(&o.z, &h2, 2); __builtin_memcpy(&o.w, &h3, 2);
  ((ushort4*)agB)[tIdx] = o;
}

// ---------------------------------------------------------------------------
// x [B,C,H] fp32 -> xT [B,H,C] fp16   (64x64 LDS transpose tiles)
// ---------------------------------------------------------------------------
__launch_bounds__(256)
__global__ void xpose(const float* __restrict__ x, __half* __restrict__ xT) {
  __shared__ float tile[64][65];
  const int b = blockIdx.z;
  const int h0 = blockIdx.x * 64;
  const int c0 = blockIdx.y * 64;
  const int lane = threadIdx.x & 63;
  const int r0 = threadIdx.x >> 6;
  const float* xb = x + (size_t)b * CC * HH;
#pragma unroll
  for (int rr = 0; rr < 16; ++rr) {
    const int c = r0 * 16 + rr;
    tile[c][lane] = xb[(size_t)(c0 + c) * HH + h0 + lane];
  }
  __syncthreads();
  __half* ob = xT + (size_t)b * HH * CC;
#pragma unroll
  for (int rr = 0; rr < 16; ++rr) {
    const int hl = r0 * 16 + rr;
    ob[(size_t)(h0 + hl) * CC + c0 + lane] = __float2half(tile[lane][hl]);
  }
}

// ---------------------------------------------------------------------------
// weight converts: w_phi/w_theta/w_g -> fp16, w_mask -> bf16 (all 131072 elems)
// ---------------------------------------------------------------------------
__global__ void convw(const float* __restrict__ s0, const float* __restrict__ s1,
                      const float* __restrict__ s2, const float* __restrict__ s3,
                      __half* __restrict__ d0, __half* __restrict__ d1,
                      __half* __restrict__ d2, __hip_bfloat16* __restrict__ d3) {
  const int which = blockIdx.y;
  const int i = (blockIdx.x * 256 + threadIdx.x) * 4;
  if (which < 3) {
    const float* s = which == 0 ? s0 : (which == 1 ? s1 : s2);
    __half* d = which == 0 ? d0 : (which == 1 ? d1 : d2);
    const float4 v = *(const float4*)(s + i);
    d[i] = __float2half(v.x); d[i + 1] = __float2half(v.y);
    d[i + 2] = __float2half(v.z); d[i + 3] = __float2half(v.w);
  } else {
    const float4 v = *(const float4*)(s3 + i);
    d3[i] = __float2bfloat16(v.x); d3[i + 1] = __float2bfloat16(v.y);
    d3[i + 2] = __float2bfloat16(v.z); d3[i + 3] = __float2bfloat16(v.w);
  }
}

// ---------------------------------------------------------------------------
// gB [B,IC,H] bf16 /= Z[b,h]  (in place, 8 elems per thread)
// ---------------------------------------------------------------------------
__launch_bounds__(256)
__global__ void gscale(unsigned int* __restrict__ g, const float* __restrict__ Z) {
  const size_t tid = (size_t)blockIdx.x * 256 + threadIdx.x;
  const size_t e0 = tid * 8;
  const int b = (int)(e0 >> 20);            // IC*H = 2^20
  const int h = (int)(e0 & (HH - 1));
  const float* Zp = Z + ((size_t)b << 12) + h;
  uint4 raw = ((const uint4*)g)[tid];
  unsigned short* u = (unsigned short*)&raw;
#pragma unroll
  for (int k = 0; k < 8; ++k) {
    const float f = __uint_as_float(((unsigned)u[k]) << 16) / Zp[k];
    const __hip_bfloat16 hb = __float2bfloat16(f);
    unsigned short bits;
    __builtin_memcpy(&bits, &hb, 2);
    u[k] = bits;
  }
  ((uint4*)g)[tid] = raw;
}

// ---------------------------------------------------------------------------
extern "C" void kernel_launch(void* const* d_in, const int* in_sizes, int n_in,
                              void* d_out, int out_size, void* d_ws, size_t ws_size,
                              hipStream_t stream) {
  (void)in_sizes; (void)n_in; (void)out_size; (void)ws_size;

  const float* x       = (const float*)d_in[0];
  const float* w_phi   = (const float*)d_in[1];
  const float* b_phi   = (const float*)d_in[2];
  const float* w_theta = (const float*)d_in[3];
  const float* b_theta = (const float*)d_in[4];
  const float* w_g     = (const float*)d_in[5];
  const float* b_g     = (const float*)d_in[6];
  const float* w_mask  = (const float*)d_in[7];
  const float* b_mask  = (const float*)d_in[8];
  float* out = (float*)d_out;

  // workspace layout (~186 MB)
  char* p = (char*)d_ws;
  __hip_bfloat16* E = (__hip_bfloat16*)p;           p += (size_t)BB * HH * HH * 2;   // 134.2 MB
  __half* xT       = (__half*)p;                    p += (size_t)BB * HH * CC * 2;   // 16.8 MB
  __half* thetaH   = (__half*)p;                    p += (size_t)BB * HH * IC * 2;   // 8.4 MB
  __half* phiH     = (__half*)p;                    p += (size_t)BB * HH * IC * 2;   // 8.4 MB
  __hip_bfloat16* gB  = (__hip_bfloat16*)p;         p += (size_t)BB * IC * HH * 2;
  __hip_bfloat16* agB = (__hip_bfloat16*)p;         p += (size_t)BB * HH * IC * 2;
  __half* wthH = (__half*)p;                        p += (size_t)IC * CC * 2;
  __half* wphH = (__half*)p;                        p += (size_t)IC * CC * 2;
  __half* wgH  = (__half*)p;                        p += (size_t)IC * CC * 2;
  __hip_bfloat16* wmB = (__hip_bfloat16*)p;         p += (size_t)CC * IC * 2;
  float* Z = (float*)p;                             p += (size_t)BB * HH * 4;
  // agF fp32 (16 MB) ALIASES thetaH+phiH (dead after the scores GEMM;
  // combined size == B*H*IC*4 bytes exactly)
  float* agF = (float*)thetaH;

  const dim3 blk(256);

  // weights -> fp16 / bf16
  convw<<<dim3(128, 4), blk, 0, stream>>>(w_phi, w_theta, w_g, w_mask, wphH, wthH, wgH, wmB);
  // x -> xT fp16
  xpose<<<dim3(HH / 64, CC / 64, BB), blk, 0, stream>>>(x, xT);

  // theta + phi, merged launch: [h,i] = xT[h,:] . w[i,:] + bias[i]
  mgemm128<0><<<dim3(IC / 128, HH / 128, BB * 2), blk, 0, stream>>>(
      xT, wthH, wphH, thetaH, phiH, b_theta, b_phi, nullptr, nullptr,
      HH, IC, CC, (size_t)HH * CC, 0, (size_t)HH * IC);
  // g[i,h] = w_g[i,:] . xT[h,:] + b_g[i]   (bf16, [IC,H])
  mgemm128<1><<<dim3(HH / 128, IC / 128, BB), blk, 0, stream>>>(
      wgH, xT, nullptr, gB, nullptr, b_g, nullptr, nullptr, nullptr,
      IC, HH, CC, 0, (size_t)HH * CC, (size_t)IC * HH);

  // scores -> E = exp(theta . phi^T), Z[b,k] = sum_q E[q,k]
  hipMemsetAsync(Z, 0, (size_t)BB * HH * sizeof(float), stream);
  mgemm128<2><<<dim3(HH / 128, HH / 128, BB), blk, 0, stream>>>(
      thetaH, phiH, nullptr, E, nullptr, nullptr, nullptr, nullptr, Z,
      HH, HH, IC, (size_t)HH * IC, (size_t)HH * IC, (size_t)HH * HH);

  // g /= Z
  gscale<<<dim3((BB * IC * HH / 8) / 256), blk, 0, stream>>>((unsigned int*)gB, Z);

  // ag[q,i] = sum_k E[q,k] * gs[i,k]  -- split-K over 4 chunks, fp32 atomics
  hipMemsetAsync(agF, 0, (size_t)BB * HH * IC * sizeof(float), stream);
  mgemm_ag<<<dim3(4, HH / 64, BB), blk, 0, stream>>>(E, gB, agF);
  cvt_ag<<<dim3((BB * HH * IC / 4) / 256), blk, 0, stream>>>(agF, agB);

  // out[c,h] = w_mask[c,:] . ag[h,:] + b_mask[c] + x[c,h]
  mgemm128<3><<<dim3(HH / 128, CC / 128, BB), blk, 0, stream>>>(
      wmB, agB, nullptr, out, nullptr, b_mask, nullptr, x, nullptr,
      CC, HH, IC, 0, (size_t)HH * IC, (size_t)CC * HH);
}